// Round 14
// baseline (223.137 us; speedup 1.0000x reference)
//
#include <hip/hip_runtime.h>
#include <stdint.h>

typedef __attribute__((ext_vector_type(8))) short bf8_t;   // 8 x bf16 (raw bits)
typedef __attribute__((ext_vector_type(4))) float f4_t;

#define DEV __device__ __forceinline__

constexpr int S_ = 1024;
constexpr float SCALE2_ = 0.104117584f;   // 1/sqrt(192) * log2(e)

DEV float bf2f(unsigned short u) { union { unsigned int i; float f; } v; v.i = ((unsigned int)u) << 16; return v.f; }
DEV unsigned short f2bf(float f) {
  union { float fv; unsigned int i; } v; v.fv = f;
  unsigned int r = v.i + 0x7FFFu + ((v.i >> 16) & 1u);
  return (unsigned short)(r >> 16);
}
DEV unsigned int pk2(float a, float b) {
  return (unsigned int)f2bf(a) | ((unsigned int)f2bf(b) << 16);
}

DEV void gll16(const unsigned short* g, unsigned short* l) {
  __builtin_amdgcn_global_load_lds(
      (const __attribute__((address_space(1))) unsigned int*)g,
      (__attribute__((address_space(3))) unsigned int*)l, 16, 0, 0);
}

// 128B-row LDS tile, chunk-XOR swizzled
DEV const bf8_t* chunk128(const unsigned short* base, int row, int ck) {
  return (const bf8_t*)((const char*)base + row * 128 + (((ck ^ row) & 7) << 4));
}

// ---------------- fp32 -> bf16 bulk conversion (8 tensors, one launch) ----
struct CvtArgs { const float* src[8]; unsigned short* dst[8]; int nchunks[8]; };

__global__ __launch_bounds__(256) void cvt_kernel(CvtArgs a, int total) {
  int idx = blockIdx.x * 256 + threadIdx.x;
  int step = gridDim.x * 256;
  for (; idx < total; idx += step) {
    int c = idx, s = 0;
    while (c >= a.nchunks[s]) { c -= a.nchunks[s]; ++s; }
    float4 v = ((const float4*)a.src[s])[c];
    ushort4 o;
    o.x = f2bf(v.x); o.y = f2bf(v.y); o.z = f2bf(v.z); o.w = f2bf(v.w);
    ((ushort4*)a.dst[s])[c] = o;
  }
}

// ---- merged QKV + REL projections: one launch, 1356 blocks ---------------
__global__ __launch_bounds__(256) void gemm_qkvrel(
    const unsigned short* __restrict__ xb, const unsigned short* __restrict__ Wqkv,
    const unsigned short* __restrict__ relb, const unsigned short* __restrict__ Wrel,
    unsigned short* __restrict__ Cqkv, unsigned short* __restrict__ Crel,
    const float* __restrict__ bq, const float* __restrict__ bk, const float* __restrict__ bv,
    const float* __restrict__ bpq, const float* __restrict__ bpk)
{
  __shared__ unsigned short At[64 * 64];
  __shared__ unsigned short Bt[128 * 64];
  const int tid = threadIdx.x, lane = tid & 63, w = tid >> 6;
  const int li = lane & 15, g = lane >> 4;
  const int wr = w >> 1, wc = w & 1;

  const int bid = blockIdx.x;
  const bool qkv = bid < 1152;
  const unsigned short *A, *B;
  int m0, n0, M, N;
  if (qkv) { m0 = (bid / 18) * 64; n0 = (bid % 18) * 128; A = xb;   B = Wqkv; M = 4096; N = 2304; }
  else     { int t = bid - 1152;
             m0 = (t / 12) * 64;  n0 = (t % 12) * 128;  A = relb; B = Wrel; M = 1025; N = 1536; }

  const int srow = tid >> 3;
  const int sl = (tid & 7) ^ (srow & 7);
  const long aoff0 = (long)min(m0 + srow,      M - 1) * 768 + sl * 8;
  const long aoff1 = (long)min(m0 + srow + 32, M - 1) * 768 + sl * 8;
  const long boff0 = (long)min(n0 + srow,      N - 1) * 768 + sl * 8;
  const long boff1 = (long)min(n0 + srow + 32, N - 1) * 768 + sl * 8;
  const long boff2 = (long)min(n0 + srow + 64, N - 1) * 768 + sl * 8;
  const long boff3 = (long)min(n0 + srow + 96, N - 1) * 768 + sl * 8;

  f4_t acc[2][4];
#pragma unroll
  for (int i = 0; i < 2; ++i)
#pragma unroll
    for (int j = 0; j < 4; ++j) acc[i][j] = f4_t{0.f, 0.f, 0.f, 0.f};

  for (int k0 = 0; k0 < 768; k0 += 64) {
    gll16(A + aoff0 + k0, At + tid * 8);
    gll16(A + aoff1 + k0, At + tid * 8 + 2048);
    gll16(B + boff0 + k0, Bt + tid * 8);
    gll16(B + boff1 + k0, Bt + tid * 8 + 2048);
    gll16(B + boff2 + k0, Bt + tid * 8 + 4096);
    gll16(B + boff3 + k0, Bt + tid * 8 + 6144);
    asm volatile("s_waitcnt vmcnt(0)" ::: "memory");
    __syncthreads();
#pragma unroll
    for (int ks = 0; ks < 2; ++ks) {
      bf8_t a[2], b[4];
#pragma unroll
      for (int fm = 0; fm < 2; ++fm)
        a[fm] = *chunk128(At, wr * 32 + fm * 16 + li, ks * 4 + g);
#pragma unroll
      for (int fn = 0; fn < 4; ++fn)
        b[fn] = *chunk128(Bt, wc * 64 + fn * 16 + li, ks * 4 + g);
#pragma unroll
      for (int fm = 0; fm < 2; ++fm)
#pragma unroll
        for (int fn = 0; fn < 4; ++fn)
          acc[fm][fn] = __builtin_amdgcn_mfma_f32_16x16x32_bf16(a[fm], b[fn], acc[fm][fn], 0, 0, 0);
    }
    __syncthreads();
  }

#pragma unroll
  for (int fm = 0; fm < 2; ++fm)
#pragma unroll
    for (int fn = 0; fn < 4; ++fn)
#pragma unroll
      for (int r = 0; r < 4; ++r) {
        int m = m0 + wr * 32 + fm * 16 + g * 4 + r;
        int n = n0 + wc * 64 + fn * 16 + li;
        if (m >= M || n >= N) continue;
        float v = acc[fm][fn][r];
        if (qkv) {
          int sel = (n >= 1536) ? 2 : (n >= 768 ? 1 : 0);
          int nn = n - sel * 768;
          v += (sel == 0 ? bq : sel == 1 ? bk : bv)[nn];
          long off = (long)sel * 3145728 + (long)((m >> 10) * 12 + (nn >> 6)) * 65536;
          if (sel == 2) off += (nn & 63) * 1024 + (m & 1023);   // V transposed
          else          off += (m & 1023) * 64 + (nn & 63);
          Cqkv[off] = f2bf(v);
        } else {
          // compact tables: [2 tbl][12 h][1025 t][64 d]
          int sel = n >= 768 ? 1 : 0;
          int nn = n - sel * 768;
          v += (sel ? bpk : bpq)[nn];
          long off = (long)sel * 787200 + (long)(nn >> 6) * 65600 + (long)m * 64 + (nn & 63);
          Crel[off] = f2bf(v);
        }
      }
}

// ---- output projection GEMM: C(fp32) = A * B^T + bias --------------------
__global__ __launch_bounds__(256) void gemm_out(
    const unsigned short* __restrict__ A,
    const unsigned short* __restrict__ B,
    float* __restrict__ C, const float* __restrict__ b0)
{
  __shared__ unsigned short At[64 * 64];
  __shared__ unsigned short Bt[128 * 64];
  const int tid = threadIdx.x, lane = tid & 63, w = tid >> 6;
  const int li = lane & 15, g = lane >> 4;
  const int wr = w >> 1, wc = w & 1;
  const int m0 = blockIdx.y * 64, n0 = blockIdx.x * 128;

  const int srow = tid >> 3;
  const int sl = (tid & 7) ^ (srow & 7);
  const long aoff0 = (long)(m0 + srow) * 768 + sl * 8;
  const long aoff1 = (long)(m0 + srow + 32) * 768 + sl * 8;
  const long boff0 = (long)(n0 + srow) * 768 + sl * 8;
  const long boff1 = (long)(n0 + srow + 32) * 768 + sl * 8;
  const long boff2 = (long)(n0 + srow + 64) * 768 + sl * 8;
  const long boff3 = (long)(n0 + srow + 96) * 768 + sl * 8;

  f4_t acc[2][4];
#pragma unroll
  for (int i = 0; i < 2; ++i)
#pragma unroll
    for (int j = 0; j < 4; ++j) acc[i][j] = f4_t{0.f, 0.f, 0.f, 0.f};

  for (int k0 = 0; k0 < 768; k0 += 64) {
    gll16(A + aoff0 + k0, At + tid * 8);
    gll16(A + aoff1 + k0, At + tid * 8 + 2048);
    gll16(B + boff0 + k0, Bt + tid * 8);
    gll16(B + boff1 + k0, Bt + tid * 8 + 2048);
    gll16(B + boff2 + k0, Bt + tid * 8 + 4096);
    gll16(B + boff3 + k0, Bt + tid * 8 + 6144);
    asm volatile("s_waitcnt vmcnt(0)" ::: "memory");
    __syncthreads();
#pragma unroll
    for (int ks = 0; ks < 2; ++ks) {
      bf8_t a[2], b[4];
#pragma unroll
      for (int fm = 0; fm < 2; ++fm)
        a[fm] = *chunk128(At, wr * 32 + fm * 16 + li, ks * 4 + g);
#pragma unroll
      for (int fn = 0; fn < 4; ++fn)
        b[fn] = *chunk128(Bt, wc * 64 + fn * 16 + li, ks * 4 + g);
#pragma unroll
      for (int fm = 0; fm < 2; ++fm)
#pragma unroll
        for (int fn = 0; fn < 4; ++fn)
          acc[fm][fn] = __builtin_amdgcn_mfma_f32_16x16x32_bf16(a[fm], b[fn], acc[fm][fn], 0, 0, 0);
    }
    __syncthreads();
  }

#pragma unroll
  for (int fm = 0; fm < 2; ++fm)
#pragma unroll
    for (int fn = 0; fn < 4; ++fn)
#pragma unroll
      for (int r = 0; r < 4; ++r) {
        int m = m0 + wr * 32 + fm * 16 + g * 4 + r;
        int n = n0 + wc * 64 + fn * 16 + li;
        C[(long)m * 768 + n] = acc[fm][fn][r] + b0[n];
      }
}

// ------- fused flash: cc + cp(per-wave strip) + pc + softmax + PV ---------
// Tpc/Tcp strips stored COLUMN-major [win][row] with b32-paired writes
// (odd-dword row strides: 18 and 66 shorts -> distinct-bank patterns).
__global__ __launch_bounds__(256) void flash_kernel(
    const unsigned short* __restrict__ Q, const unsigned short* __restrict__ Kc,
    const unsigned short* __restrict__ kr, const unsigned short* __restrict__ qr,
    const unsigned short* __restrict__ Vt, unsigned short* __restrict__ ctx)
{
  // bijective XCD swizzle: each XCD owns 6 whole bh (all 16 i-tiles together)
  const int flat = blockIdx.x;
  const int logical = (flat & 7) * 96 + (flat >> 3);
  const int bh = logical >> 4, h = bh % 12, bb = bh / 12;
  const int i0 = (logical & 15) * 64;
  const int tid = threadIdx.x, lane = tid & 63, w = tid >> 6;
  const int g = lane >> 4, li = lane & 15;
  const unsigned short* Qb  = Q  + (long)bh * (S_ * 64);
  const unsigned short* Kb  = Kc + (long)bh * (S_ * 64);
  const unsigned short* Vb  = Vt + (long)bh * (S_ * 64);   // [64 d][1024 s]
  const unsigned short* krh = kr + (long)h * 65600;        // compact [1025][64]
  const unsigned short* qrh = qr + (long)h * 65600;

  __shared__ unsigned short Kt[4096];          // single buf, 64x64, XOR-swizzled chunks
  __shared__ unsigned short Vl[4096];          // single buf
  __shared__ unsigned short TpcS[128 * 66];    // col-major [win][j], b32-paired
  __shared__ unsigned short TcpS[4 * 80 * 18]; // per-wave col-major [win][i_row]
  __shared__ unsigned short Pl[4096];          // per-wave P rows, XOR-swizzled

  const int mh = w & 1, nq = w >> 1;

  // stage K-tile + V-tile for tile jt (source-preswizzled, linear LDS dest)
  const int sr0 = w * 8 + (lane >> 3);
  const int scc = (lane & 7) ^ (sr0 & 7);
  auto stage = [&](int jt) {
    const int j0n = jt * 64;
    gll16(Kb + (long)(j0n + sr0) * 64 + scc * 8,        &Kt[w * 512 + lane * 8]);
    gll16(Kb + (long)(j0n + sr0 + 32) * 64 + scc * 8,   &Kt[w * 512 + 2048 + lane * 8]);
    gll16(Vb + (long)sr0 * 1024 + j0n + scc * 8,        &Vl[w * 512 + lane * 8]);
    gll16(Vb + (long)(sr0 + 32) * 1024 + j0n + scc * 8, &Vl[w * 512 + 2048 + lane * 8]);
  };

  // hoisted Q fragments: wave w owns rows i0 + w*16 .. +16
  bf8_t q3[2];
#pragma unroll
  for (int ks = 0; ks < 2; ++ks)
    q3[ks] = *(const bf8_t*)(Qb + (long)(i0 + w * 16 + li) * 64 + ks * 32 + g * 8);

  // no-max softmax: per-lane partial denominators, reduced once at epilogue
  float l_p[4] = {0.f, 0.f, 0.f, 0.f};
  f4_t acc_o[4];
#pragma unroll
  for (int fn = 0; fn < 4; ++fn) acc_o[fn] = f4_t{0.f, 0.f, 0.f, 0.f};

  const int base_cp = li + 15 - g * 4;          // + fn*16 - r  -> [0,78]
  const int base_pc = 63 + w * 16 + g * 4 - li; // + r - fn*16  -> [0,126]

  stage(0);

  for (int jt = 0; jt < 16; ++jt) {
    const int j0 = jt * 64;
    const int Dl = j0 - i0;
    const int wbU = Dl - w * 16 - 15 + 512;     // unclamped strip base
    const int rbU = 449 - Dl;                   // unclamped Tpc window base

    { // Tcp phase (regs + own strip; no K/V dep — covers stage latency)
      f4_t at[5];
#pragma unroll
      for (int f5 = 0; f5 < 5; ++f5) at[f5] = f4_t{0.f, 0.f, 0.f, 0.f};
#pragma unroll
      for (int ks = 0; ks < 2; ++ks) {
        bf8_t b[5];
#pragma unroll
        for (int f5 = 0; f5 < 5; ++f5) {
          int krow = min(max(wbU + f5 * 16 + li, 0), 1024);   // per-row clamp
          b[f5] = *(const bf8_t*)(krh + (long)krow * 64 + ks * 32 + g * 8);
        }
#pragma unroll
        for (int f5 = 0; f5 < 5; ++f5)
          at[f5] = __builtin_amdgcn_mfma_f32_16x16x32_bf16(q3[ks], b[f5], at[f5], 0, 0, 0);
      }
      // packed col-major store: TcpS[w][win = f5*16+li][i_row]
#pragma unroll
      for (int f5 = 0; f5 < 5; ++f5) {
        int base = w * 1440 + (f5 * 16 + li) * 18 + g * 4;
        *(unsigned int*)&TcpS[base]     = pk2(at[f5][0], at[f5][1]);
        *(unsigned int*)&TcpS[base + 2] = pk2(at[f5][2], at[f5][3]);
      }
    }

    asm volatile("s_waitcnt vmcnt(0)" ::: "memory");
    __builtin_amdgcn_s_barrier();              // A: K,V staged & visible

    { // Tpc = Ktile(64x64) @ qrWin(128x64)^T  (A from swizzled LDS)
      f4_t acc[2][4];
#pragma unroll
      for (int i = 0; i < 2; ++i)
#pragma unroll
        for (int j = 0; j < 4; ++j) acc[i][j] = f4_t{0.f, 0.f, 0.f, 0.f};
#pragma unroll
      for (int ks = 0; ks < 2; ++ks) {
        bf8_t a[2], b[4];
#pragma unroll
        for (int fm = 0; fm < 2; ++fm)
          a[fm] = *chunk128(Kt, mh * 32 + fm * 16 + li, ks * 4 + g);
#pragma unroll
        for (int fn = 0; fn < 4; ++fn) {
          int qrow = min(max(rbU + nq * 64 + fn * 16 + li, 0), 1024);  // per-row clamp
          b[fn] = *(const bf8_t*)(qrh + (long)qrow * 64 + ks * 32 + g * 8);
        }
#pragma unroll
        for (int fm = 0; fm < 2; ++fm)
#pragma unroll
          for (int fn = 0; fn < 4; ++fn)
            acc[fm][fn] = __builtin_amdgcn_mfma_f32_16x16x32_bf16(a[fm], b[fn], acc[fm][fn], 0, 0, 0);
      }
      // packed col-major store: TpcS[win = nq*64+fn*16+li][j = mh*32+fm*16+g*4+r]
#pragma unroll
      for (int fm = 0; fm < 2; ++fm)
#pragma unroll
        for (int fn = 0; fn < 4; ++fn) {
          int base = (nq * 64 + fn * 16 + li) * 66 + mh * 32 + fm * 16 + g * 4;
          *(unsigned int*)&TpcS[base]     = pk2(acc[fm][fn][0], acc[fm][fn][1]);
          *(unsigned int*)&TpcS[base + 2] = pk2(acc[fm][fn][2], acc[fm][fn][3]);
        }
    }

    asm volatile("s_waitcnt lgkmcnt(0)" ::: "memory");
    __builtin_amdgcn_s_barrier();              // B: TpcS visible

    // cc MFMA — wave w: rows [w*16, w*16+16), all 64 cols
    f4_t s4[4];
#pragma unroll
    for (int fn = 0; fn < 4; ++fn) s4[fn] = f4_t{0.f, 0.f, 0.f, 0.f};
#pragma unroll
    for (int ks = 0; ks < 2; ++ks) {
      bf8_t b[4];
#pragma unroll
      for (int fn = 0; fn < 4; ++fn)
        b[fn] = *chunk128(Kt, fn * 16 + li, ks * 4 + g);
#pragma unroll
      for (int fn = 0; fn < 4; ++fn)
        s4[fn] = __builtin_amdgcn_mfma_f32_16x16x32_bf16(q3[ks], b[fn], s4[fn], 0, 0, 0);
    }

    // gather cp + pc from col-major strips; exp2; partial denom; P to LDS
#pragma unroll
    for (int fn = 0; fn < 4; ++fn)
#pragma unroll
      for (int r = 0; r < 4; ++r) {
        float v = s4[fn][r]
                + bf2f(TcpS[w * 1440 + (base_cp + fn * 16 - r) * 18 + g * 4 + r])
                + bf2f(TpcS[(base_pc + r - fn * 16) * 66 + fn * 16 + li]);
        float p = exp2f(v * SCALE2_);
        l_p[r] += p;
        const int row = w * 16 + g * 4 + r;
        int byte = row * 128 + (fn * 16 + li) * 2;
        byte ^= (row & 7) << 4;
        *(unsigned short*)((char*)Pl + byte) = f2bf(p);
      }

    // PV: acc_o += P(16x64) @ V^T
#pragma unroll
    for (int ks = 0; ks < 2; ++ks) {
      const int arow = w * 16 + li;
      int abyte = arow * 128 + ks * 64 + g * 16;
      abyte ^= (arow & 7) << 4;
      bf8_t a = *(const bf8_t*)((const char*)Pl + abyte);
      bf8_t b[4];
#pragma unroll
      for (int fn2 = 0; fn2 < 4; ++fn2)
        b[fn2] = *chunk128(Vl, fn2 * 16 + li, ks * 4 + g);
#pragma unroll
      for (int fn2 = 0; fn2 < 4; ++fn2)
        acc_o[fn2] = __builtin_amdgcn_mfma_f32_16x16x32_bf16(a, b[fn2], acc_o[fn2], 0, 0, 0);
    }

    if (jt + 1 < 16) {
      __builtin_amdgcn_s_barrier();            // C: all waves done reading Kt/Vl
      stage(jt + 1);                            // latency covered by next Tcp phase
    }
  }

  // epilogue: one 16-lane reduction of the deferred denominators, then write
#pragma unroll
  for (int r = 0; r < 4; ++r)
#pragma unroll
    for (int off = 1; off < 16; off <<= 1) l_p[r] += __shfl_xor(l_p[r], off);
  float inv[4];
#pragma unroll
  for (int r = 0; r < 4; ++r) inv[r] = 1.0f / l_p[r];
#pragma unroll
  for (int fn2 = 0; fn2 < 4; ++fn2)
#pragma unroll
    for (int r = 0; r < 4; ++r) {
      const int row = i0 + w * 16 + g * 4 + r;
      const int d = fn2 * 16 + li;
      float v = acc_o[fn2][r] * inv[r];
      ctx[((long)bb * 1024 + row) * 768 + h * 64 + d] = f2bf(v);
    }
}

// ---------------- host launch ---------------------------------------------
extern "C" void kernel_launch(void* const* d_in, const int* in_sizes, int n_in,
                              void* d_out, int out_size, void* d_ws, size_t ws_size,
                              hipStream_t stream)
{
  const float* x   = (const float*)d_in[0];
  const float* Wq  = (const float*)d_in[1];
  const float* bq  = (const float*)d_in[2];
  const float* Wk  = (const float*)d_in[3];
  const float* bk  = (const float*)d_in[4];
  const float* Wv  = (const float*)d_in[5];
  const float* bv  = (const float*)d_in[6];
  const float* Wpq = (const float*)d_in[7];
  const float* bpq = (const float*)d_in[8];
  const float* Wpk = (const float*)d_in[9];
  const float* bpk = (const float*)d_in[10];
  const float* rel = (const float*)d_in[11];
  const float* Wo  = (const float*)d_in[12];
  const float* bo  = (const float*)d_in[13];

  char* ws = (char*)d_ws;
  auto alloc = [&](size_t bytes) { char* p = ws; ws += (bytes + 255) & ~(size_t)255; return p; };
  unsigned short* xb   = (unsigned short*)alloc((size_t)4096 * 768 * 2);
  unsigned short* Wqb  = (unsigned short*)alloc((size_t)768 * 768 * 2);   // contiguous Wq|Wk|Wv
  unsigned short* Wkb  = (unsigned short*)alloc((size_t)768 * 768 * 2);
  unsigned short* Wvb  = (unsigned short*)alloc((size_t)768 * 768 * 2);
  unsigned short* Wpqb = (unsigned short*)alloc((size_t)768 * 768 * 2);   // contiguous Wpq|Wpk
  unsigned short* Wpkb = (unsigned short*)alloc((size_t)768 * 768 * 2);
  unsigned short* Wob  = (unsigned short*)alloc((size_t)768 * 768 * 2);
  unsigned short* relb = (unsigned short*)alloc((size_t)1025 * 768 * 2);
  unsigned short* Qb   = (unsigned short*)alloc((size_t)48 * 1024 * 64 * 2);  // contiguous Q|K|Vt
  unsigned short* Kb   = (unsigned short*)alloc((size_t)48 * 1024 * 64 * 2);
  unsigned short* Vt   = (unsigned short*)alloc((size_t)48 * 64 * 1024 * 2);
  unsigned short* qkx  = (unsigned short*)alloc((size_t)2 * 12 * 1025 * 64 * 2); // compact qr|kr
  unsigned short* ctx  = (unsigned short*)alloc((size_t)4096 * 768 * 2);

  CvtArgs ca;
  const float* srcs[8] = {x, Wq, Wk, Wv, Wpq, Wpk, Wo, rel};
  unsigned short* dsts[8] = {xb, Wqb, Wkb, Wvb, Wpqb, Wpkb, Wob, relb};
  const int nch[8] = {786432, 147456, 147456, 147456, 147456, 147456, 147456, 196800};
  int total = 0;
  for (int i = 0; i < 8; ++i) { ca.src[i] = srcs[i]; ca.dst[i] = dsts[i]; ca.nchunks[i] = nch[i]; total += nch[i]; }
  cvt_kernel<<<dim3(2048), dim3(256), 0, stream>>>(ca, total);

  dim3 blk(256);
  // merged QKV + REL projections (1356 blocks, one launch)
  gemm_qkvrel<<<dim3(1356), blk, 0, stream>>>(xb, Wqb, relb, Wpqb, Qb, qkx,
                                              bq, bk, bv, bpq, bpk);
  // fused scores(cc+cp+pc) + softmax + PV  (768 blocks, XCD-swizzled, 3/CU)
  flash_kernel<<<dim3(768), blk, 0, stream>>>(Qb, Kb, qkx + 787200, qkx, Vt, ctx);
  // output projection: [4096,768] x [768,768]^T -> fp32 d_out
  gemm_out<<<dim3(6, 64), blk, 0, stream>>>(ctx, Wob, (float*)d_out, bo);

  (void)in_sizes; (void)n_in; (void)out_size; (void)ws_size;
}

// Round 15
// 192.172 us; speedup vs baseline: 1.1611x; 1.1611x over previous
//
#include <hip/hip_runtime.h>
#include <stdint.h>

typedef __attribute__((ext_vector_type(8))) short bf8_t;   // 8 x bf16 (raw bits)
typedef __attribute__((ext_vector_type(4))) float f4_t;

#define DEV __device__ __forceinline__

constexpr int S_ = 1024;
constexpr float SCALE2_ = 0.104117584f;   // 1/sqrt(192) * log2(e)

DEV float bf2f(unsigned short u) { union { unsigned int i; float f; } v; v.i = ((unsigned int)u) << 16; return v.f; }
DEV unsigned short f2bf(float f) {
  union { float fv; unsigned int i; } v; v.fv = f;
  unsigned int r = v.i + 0x7FFFu + ((v.i >> 16) & 1u);
  return (unsigned short)(r >> 16);
}

DEV void gll16(const unsigned short* g, unsigned short* l) {
  __builtin_amdgcn_global_load_lds(
      (const __attribute__((address_space(1))) unsigned int*)g,
      (__attribute__((address_space(3))) unsigned int*)l, 16, 0, 0);
}

// 128B-row LDS tile, chunk-XOR swizzled
DEV const bf8_t* chunk128(const unsigned short* base, int row, int ck) {
  return (const bf8_t*)((const char*)base + row * 128 + (((ck ^ row) & 7) << 4));
}

// ---------------- fp32 -> bf16 bulk conversion (8 tensors, one launch) ----
struct CvtArgs { const float* src[8]; unsigned short* dst[8]; int nchunks[8]; };

__global__ __launch_bounds__(256) void cvt_kernel(CvtArgs a, int total) {
  int idx = blockIdx.x * 256 + threadIdx.x;
  int step = gridDim.x * 256;
  for (; idx < total; idx += step) {
    int c = idx, s = 0;
    while (c >= a.nchunks[s]) { c -= a.nchunks[s]; ++s; }
    float4 v = ((const float4*)a.src[s])[c];
    ushort4 o;
    o.x = f2bf(v.x); o.y = f2bf(v.y); o.z = f2bf(v.z); o.w = f2bf(v.w);
    ((ushort4*)a.dst[s])[c] = o;
  }
}

// ---- merged QKV + REL projections: one launch, 1356 blocks ---------------
__global__ __launch_bounds__(256) void gemm_qkvrel(
    const unsigned short* __restrict__ xb, const unsigned short* __restrict__ Wqkv,
    const unsigned short* __restrict__ relb, const unsigned short* __restrict__ Wrel,
    unsigned short* __restrict__ Cqkv, unsigned short* __restrict__ Crel,
    const float* __restrict__ bq, const float* __restrict__ bk, const float* __restrict__ bv,
    const float* __restrict__ bpq, const float* __restrict__ bpk)
{
  __shared__ unsigned short At[64 * 64];
  __shared__ unsigned short Bt[128 * 64];
  const int tid = threadIdx.x, lane = tid & 63, w = tid >> 6;
  const int li = lane & 15, g = lane >> 4;
  const int wr = w >> 1, wc = w & 1;

  const int bid = blockIdx.x;
  const bool qkv = bid < 1152;
  const unsigned short *A, *B;
  int m0, n0, M, N;
  if (qkv) { m0 = (bid / 18) * 64; n0 = (bid % 18) * 128; A = xb;   B = Wqkv; M = 4096; N = 2304; }
  else     { int t = bid - 1152;
             m0 = (t / 12) * 64;  n0 = (t % 12) * 128;  A = relb; B = Wrel; M = 1025; N = 1536; }

  const int srow = tid >> 3;
  const int sl = (tid & 7) ^ (srow & 7);
  const long aoff0 = (long)min(m0 + srow,      M - 1) * 768 + sl * 8;
  const long aoff1 = (long)min(m0 + srow + 32, M - 1) * 768 + sl * 8;
  const long boff0 = (long)min(n0 + srow,      N - 1) * 768 + sl * 8;
  const long boff1 = (long)min(n0 + srow + 32, N - 1) * 768 + sl * 8;
  const long boff2 = (long)min(n0 + srow + 64, N - 1) * 768 + sl * 8;
  const long boff3 = (long)min(n0 + srow + 96, N - 1) * 768 + sl * 8;

  f4_t acc[2][4];
#pragma unroll
  for (int i = 0; i < 2; ++i)
#pragma unroll
    for (int j = 0; j < 4; ++j) acc[i][j] = f4_t{0.f, 0.f, 0.f, 0.f};

  for (int k0 = 0; k0 < 768; k0 += 64) {
    gll16(A + aoff0 + k0, At + tid * 8);
    gll16(A + aoff1 + k0, At + tid * 8 + 2048);
    gll16(B + boff0 + k0, Bt + tid * 8);
    gll16(B + boff1 + k0, Bt + tid * 8 + 2048);
    gll16(B + boff2 + k0, Bt + tid * 8 + 4096);
    gll16(B + boff3 + k0, Bt + tid * 8 + 6144);
    asm volatile("s_waitcnt vmcnt(0)" ::: "memory");
    __syncthreads();
#pragma unroll
    for (int ks = 0; ks < 2; ++ks) {
      bf8_t a[2], b[4];
#pragma unroll
      for (int fm = 0; fm < 2; ++fm)
        a[fm] = *chunk128(At, wr * 32 + fm * 16 + li, ks * 4 + g);
#pragma unroll
      for (int fn = 0; fn < 4; ++fn)
        b[fn] = *chunk128(Bt, wc * 64 + fn * 16 + li, ks * 4 + g);
#pragma unroll
      for (int fm = 0; fm < 2; ++fm)
#pragma unroll
        for (int fn = 0; fn < 4; ++fn)
          acc[fm][fn] = __builtin_amdgcn_mfma_f32_16x16x32_bf16(a[fm], b[fn], acc[fm][fn], 0, 0, 0);
    }
    __syncthreads();
  }

#pragma unroll
  for (int fm = 0; fm < 2; ++fm)
#pragma unroll
    for (int fn = 0; fn < 4; ++fn)
#pragma unroll
      for (int r = 0; r < 4; ++r) {
        int m = m0 + wr * 32 + fm * 16 + g * 4 + r;
        int n = n0 + wc * 64 + fn * 16 + li;
        if (m >= M || n >= N) continue;
        float v = acc[fm][fn][r];
        if (qkv) {
          int sel = (n >= 1536) ? 2 : (n >= 768 ? 1 : 0);
          int nn = n - sel * 768;
          v += (sel == 0 ? bq : sel == 1 ? bk : bv)[nn];
          long off = (long)sel * 3145728 + (long)((m >> 10) * 12 + (nn >> 6)) * 65536;
          if (sel == 2) off += (nn & 63) * 1024 + (m & 1023);   // V transposed
          else          off += (m & 1023) * 64 + (nn & 63);
          Cqkv[off] = f2bf(v);
        } else {
          // compact tables: [2 tbl][12 h][1025 t][64 d]
          int sel = n >= 768 ? 1 : 0;
          int nn = n - sel * 768;
          v += (sel ? bpk : bpq)[nn];
          long off = (long)sel * 787200 + (long)(nn >> 6) * 65600 + (long)m * 64 + (nn & 63);
          Crel[off] = f2bf(v);
        }
      }
}

// ---- output projection GEMM: C(fp32) = A * B^T + bias --------------------
__global__ __launch_bounds__(256) void gemm_out(
    const unsigned short* __restrict__ A,
    const unsigned short* __restrict__ B,
    float* __restrict__ C, const float* __restrict__ b0)
{
  __shared__ unsigned short At[64 * 64];
  __shared__ unsigned short Bt[128 * 64];
  const int tid = threadIdx.x, lane = tid & 63, w = tid >> 6;
  const int li = lane & 15, g = lane >> 4;
  const int wr = w >> 1, wc = w & 1;
  const int m0 = blockIdx.y * 64, n0 = blockIdx.x * 128;

  const int srow = tid >> 3;
  const int sl = (tid & 7) ^ (srow & 7);
  const long aoff0 = (long)(m0 + srow) * 768 + sl * 8;
  const long aoff1 = (long)(m0 + srow + 32) * 768 + sl * 8;
  const long boff0 = (long)(n0 + srow) * 768 + sl * 8;
  const long boff1 = (long)(n0 + srow + 32) * 768 + sl * 8;
  const long boff2 = (long)(n0 + srow + 64) * 768 + sl * 8;
  const long boff3 = (long)(n0 + srow + 96) * 768 + sl * 8;

  f4_t acc[2][4];
#pragma unroll
  for (int i = 0; i < 2; ++i)
#pragma unroll
    for (int j = 0; j < 4; ++j) acc[i][j] = f4_t{0.f, 0.f, 0.f, 0.f};

  for (int k0 = 0; k0 < 768; k0 += 64) {
    gll16(A + aoff0 + k0, At + tid * 8);
    gll16(A + aoff1 + k0, At + tid * 8 + 2048);
    gll16(B + boff0 + k0, Bt + tid * 8);
    gll16(B + boff1 + k0, Bt + tid * 8 + 2048);
    gll16(B + boff2 + k0, Bt + tid * 8 + 4096);
    gll16(B + boff3 + k0, Bt + tid * 8 + 6144);
    asm volatile("s_waitcnt vmcnt(0)" ::: "memory");
    __syncthreads();
#pragma unroll
    for (int ks = 0; ks < 2; ++ks) {
      bf8_t a[2], b[4];
#pragma unroll
      for (int fm = 0; fm < 2; ++fm)
        a[fm] = *chunk128(At, wr * 32 + fm * 16 + li, ks * 4 + g);
#pragma unroll
      for (int fn = 0; fn < 4; ++fn)
        b[fn] = *chunk128(Bt, wc * 64 + fn * 16 + li, ks * 4 + g);
#pragma unroll
      for (int fm = 0; fm < 2; ++fm)
#pragma unroll
        for (int fn = 0; fn < 4; ++fn)
          acc[fm][fn] = __builtin_amdgcn_mfma_f32_16x16x32_bf16(a[fm], b[fn], acc[fm][fn], 0, 0, 0);
    }
    __syncthreads();
  }

#pragma unroll
  for (int fm = 0; fm < 2; ++fm)
#pragma unroll
    for (int fn = 0; fn < 4; ++fn)
#pragma unroll
      for (int r = 0; r < 4; ++r) {
        int m = m0 + wr * 32 + fm * 16 + g * 4 + r;
        int n = n0 + wc * 64 + fn * 16 + li;
        C[(long)m * 768 + n] = acc[fm][fn][r] + b0[n];
      }
}

// ------- fused flash (r13 body): cc + cp(per-wave strip) + pc + softmax + PV
__global__ __launch_bounds__(256) void flash_kernel(
    const unsigned short* __restrict__ Q, const unsigned short* __restrict__ Kc,
    const unsigned short* __restrict__ kr, const unsigned short* __restrict__ qr,
    const unsigned short* __restrict__ Vt, unsigned short* __restrict__ ctx)
{
  // bijective XCD swizzle: each XCD owns 6 whole bh (all 16 i-tiles together)
  const int flat = blockIdx.x;
  const int logical = (flat & 7) * 96 + (flat >> 3);
  const int bh = logical >> 4, h = bh % 12, bb = bh / 12;
  const int i0 = (logical & 15) * 64;
  const int tid = threadIdx.x, lane = tid & 63, w = tid >> 6;
  const int g = lane >> 4, li = lane & 15;
  const unsigned short* Qb  = Q  + (long)bh * (S_ * 64);
  const unsigned short* Kb  = Kc + (long)bh * (S_ * 64);
  const unsigned short* Vb  = Vt + (long)bh * (S_ * 64);   // [64 d][1024 s]
  const unsigned short* krh = kr + (long)h * 65600;        // compact [1025][64]
  const unsigned short* qrh = qr + (long)h * 65600;

  __shared__ unsigned short Kt[4096];        // single buf, 64x64, XOR-swizzled chunks
  __shared__ unsigned short Vl[4096];        // single buf
  __shared__ unsigned short Tpc[64][132];
  __shared__ unsigned short TcpW[4][16][84]; // per-wave cp strips (42 dw/row)
  __shared__ unsigned short Pl[4096];        // per-wave P rows, XOR-swizzled

  const int mh = w & 1, nq = w >> 1;

  // stage K-tile + V-tile for tile jt (source-preswizzled, linear LDS dest)
  const int sr0 = w * 8 + (lane >> 3);
  const int scc = (lane & 7) ^ (sr0 & 7);
  auto stage = [&](int jt) {
    const int j0n = jt * 64;
    gll16(Kb + (long)(j0n + sr0) * 64 + scc * 8,        &Kt[w * 512 + lane * 8]);
    gll16(Kb + (long)(j0n + sr0 + 32) * 64 + scc * 8,   &Kt[w * 512 + 2048 + lane * 8]);
    gll16(Vb + (long)sr0 * 1024 + j0n + scc * 8,        &Vl[w * 512 + lane * 8]);
    gll16(Vb + (long)(sr0 + 32) * 1024 + j0n + scc * 8, &Vl[w * 512 + 2048 + lane * 8]);
  };

  // hoisted Q fragments: wave w owns rows i0 + w*16 .. +16
  bf8_t q3[2];
#pragma unroll
  for (int ks = 0; ks < 2; ++ks)
    q3[ks] = *(const bf8_t*)(Qb + (long)(i0 + w * 16 + li) * 64 + ks * 32 + g * 8);

  // no-max softmax: per-lane partial denominators, reduced once at epilogue
  float l_p[4] = {0.f, 0.f, 0.f, 0.f};
  f4_t acc_o[4];
#pragma unroll
  for (int fn = 0; fn < 4; ++fn) acc_o[fn] = f4_t{0.f, 0.f, 0.f, 0.f};

  const int base_cp = li + 15 - g * 4;          // + fn*16 - r  -> [0,78]
  const int base_pc = 63 + w * 16 + g * 4 - li; // + r - fn*16  -> [0,126]

  stage(0);

  for (int jt = 0; jt < 16; ++jt) {
    const int j0 = jt * 64;
    const int Dl = j0 - i0;
    const int wbU = Dl - w * 16 - 15 + 512;     // unclamped strip base
    const int rbU = 449 - Dl;                   // unclamped Tpc window base

    { // Tcp phase (regs + own strip; no K/V dep — covers stage latency)
      f4_t at[5];
#pragma unroll
      for (int f5 = 0; f5 < 5; ++f5) at[f5] = f4_t{0.f, 0.f, 0.f, 0.f};
#pragma unroll
      for (int ks = 0; ks < 2; ++ks) {
        bf8_t b[5];
#pragma unroll
        for (int f5 = 0; f5 < 5; ++f5) {
          int krow = min(max(wbU + f5 * 16 + li, 0), 1024);   // per-row clamp
          b[f5] = *(const bf8_t*)(krh + (long)krow * 64 + ks * 32 + g * 8);
        }
#pragma unroll
        for (int f5 = 0; f5 < 5; ++f5)
          at[f5] = __builtin_amdgcn_mfma_f32_16x16x32_bf16(q3[ks], b[f5], at[f5], 0, 0, 0);
      }
#pragma unroll
      for (int f5 = 0; f5 < 5; ++f5)
#pragma unroll
        for (int r = 0; r < 4; ++r)
          TcpW[w][g * 4 + r][f5 * 16 + li] = f2bf(at[f5][r]);
    }

    asm volatile("s_waitcnt vmcnt(0)" ::: "memory");
    __builtin_amdgcn_s_barrier();              // A: K,V staged & visible

    { // Tpc = Ktile(64x64) @ qrWin(128x64)^T  (A from swizzled LDS)
      f4_t acc[2][4];
#pragma unroll
      for (int i = 0; i < 2; ++i)
#pragma unroll
        for (int j = 0; j < 4; ++j) acc[i][j] = f4_t{0.f, 0.f, 0.f, 0.f};
#pragma unroll
      for (int ks = 0; ks < 2; ++ks) {
        bf8_t a[2], b[4];
#pragma unroll
        for (int fm = 0; fm < 2; ++fm)
          a[fm] = *chunk128(Kt, mh * 32 + fm * 16 + li, ks * 4 + g);
#pragma unroll
        for (int fn = 0; fn < 4; ++fn) {
          int qrow = min(max(rbU + nq * 64 + fn * 16 + li, 0), 1024);  // per-row clamp
          b[fn] = *(const bf8_t*)(qrh + (long)qrow * 64 + ks * 32 + g * 8);
        }
#pragma unroll
        for (int fm = 0; fm < 2; ++fm)
#pragma unroll
          for (int fn = 0; fn < 4; ++fn)
            acc[fm][fn] = __builtin_amdgcn_mfma_f32_16x16x32_bf16(a[fm], b[fn], acc[fm][fn], 0, 0, 0);
      }
#pragma unroll
      for (int fm = 0; fm < 2; ++fm)
#pragma unroll
        for (int fn = 0; fn < 4; ++fn)
#pragma unroll
          for (int r = 0; r < 4; ++r)
            Tpc[mh * 32 + fm * 16 + g * 4 + r][nq * 64 + fn * 16 + li] = f2bf(acc[fm][fn][r]);
    }

    asm volatile("s_waitcnt lgkmcnt(0)" ::: "memory");
    __builtin_amdgcn_s_barrier();              // B: Tpc visible

    // cc MFMA — wave w: rows [w*16, w*16+16), all 64 cols
    f4_t s4[4];
#pragma unroll
    for (int fn = 0; fn < 4; ++fn) s4[fn] = f4_t{0.f, 0.f, 0.f, 0.f};
#pragma unroll
    for (int ks = 0; ks < 2; ++ks) {
      bf8_t b[4];
#pragma unroll
      for (int fn = 0; fn < 4; ++fn)
        b[fn] = *chunk128(Kt, fn * 16 + li, ks * 4 + g);
#pragma unroll
      for (int fn = 0; fn < 4; ++fn)
        s4[fn] = __builtin_amdgcn_mfma_f32_16x16x32_bf16(q3[ks], b[fn], s4[fn], 0, 0, 0);
    }

    // gather cp + pc; exp2 (no max subtraction); partial denom; P to LDS
#pragma unroll
    for (int fn = 0; fn < 4; ++fn)
#pragma unroll
      for (int r = 0; r < 4; ++r) {
        float v = s4[fn][r] + bf2f(TcpW[w][g * 4 + r][base_cp + fn * 16 - r])
                            + bf2f(Tpc[fn * 16 + li][base_pc + r - fn * 16]);
        float p = exp2f(v * SCALE2_);
        l_p[r] += p;
        const int row = w * 16 + g * 4 + r;
        int byte = row * 128 + (fn * 16 + li) * 2;
        byte ^= (row & 7) << 4;
        *(unsigned short*)((char*)Pl + byte) = f2bf(p);
      }

    // PV: acc_o += P(16x64) @ V^T
#pragma unroll
    for (int ks = 0; ks < 2; ++ks) {
      const int arow = w * 16 + li;
      int abyte = arow * 128 + ks * 64 + g * 16;
      abyte ^= (arow & 7) << 4;
      bf8_t a = *(const bf8_t*)((const char*)Pl + abyte);
      bf8_t b[4];
#pragma unroll
      for (int fn2 = 0; fn2 < 4; ++fn2)
        b[fn2] = *chunk128(Vl, fn2 * 16 + li, ks * 4 + g);
#pragma unroll
      for (int fn2 = 0; fn2 < 4; ++fn2)
        acc_o[fn2] = __builtin_amdgcn_mfma_f32_16x16x32_bf16(a, b[fn2], acc_o[fn2], 0, 0, 0);
    }

    if (jt + 1 < 16) {
      __builtin_amdgcn_s_barrier();            // C: all waves done reading Kt/Vl
      stage(jt + 1);                            // latency covered by next Tcp phase
    }
  }

  // epilogue: one 16-lane reduction of the deferred denominators, then write
#pragma unroll
  for (int r = 0; r < 4; ++r)
#pragma unroll
    for (int off = 1; off < 16; off <<= 1) l_p[r] += __shfl_xor(l_p[r], off);
  float inv[4];
#pragma unroll
  for (int r = 0; r < 4; ++r) inv[r] = 1.0f / l_p[r];
#pragma unroll
  for (int fn2 = 0; fn2 < 4; ++fn2)
#pragma unroll
    for (int r = 0; r < 4; ++r) {
      const int row = i0 + w * 16 + g * 4 + r;
      const int d = fn2 * 16 + li;
      float v = acc_o[fn2][r] * inv[r];
      ctx[((long)bb * 1024 + row) * 768 + h * 64 + d] = f2bf(v);
    }
}

// ---------------- host launch ---------------------------------------------
extern "C" void kernel_launch(void* const* d_in, const int* in_sizes, int n_in,
                              void* d_out, int out_size, void* d_ws, size_t ws_size,
                              hipStream_t stream)
{
  const float* x   = (const float*)d_in[0];
  const float* Wq  = (const float*)d_in[1];
  const float* bq  = (const float*)d_in[2];
  const float* Wk  = (const float*)d_in[3];
  const float* bk  = (const float*)d_in[4];
  const float* Wv  = (const float*)d_in[5];
  const float* bv  = (const float*)d_in[6];
  const float* Wpq = (const float*)d_in[7];
  const float* bpq = (const float*)d_in[8];
  const float* Wpk = (const float*)d_in[9];
  const float* bpk = (const float*)d_in[10];
  const float* rel = (const float*)d_in[11];
  const float* Wo  = (const float*)d_in[12];
  const float* bo  = (const float*)d_in[13];

  char* ws = (char*)d_ws;
  auto alloc = [&](size_t bytes) { char* p = ws; ws += (bytes + 255) & ~(size_t)255; return p; };
  unsigned short* xb   = (unsigned short*)alloc((size_t)4096 * 768 * 2);
  unsigned short* Wqb  = (unsigned short*)alloc((size_t)768 * 768 * 2);   // contiguous Wq|Wk|Wv
  unsigned short* Wkb  = (unsigned short*)alloc((size_t)768 * 768 * 2);
  unsigned short* Wvb  = (unsigned short*)alloc((size_t)768 * 768 * 2);
  unsigned short* Wpqb = (unsigned short*)alloc((size_t)768 * 768 * 2);   // contiguous Wpq|Wpk
  unsigned short* Wpkb = (unsigned short*)alloc((size_t)768 * 768 * 2);
  unsigned short* Wob  = (unsigned short*)alloc((size_t)768 * 768 * 2);
  unsigned short* relb = (unsigned short*)alloc((size_t)1025 * 768 * 2);
  unsigned short* Qb   = (unsigned short*)alloc((size_t)48 * 1024 * 64 * 2);  // contiguous Q|K|Vt
  unsigned short* Kb   = (unsigned short*)alloc((size_t)48 * 1024 * 64 * 2);
  unsigned short* Vt   = (unsigned short*)alloc((size_t)48 * 64 * 1024 * 2);
  unsigned short* qkx  = (unsigned short*)alloc((size_t)2 * 12 * 1025 * 64 * 2); // compact qr|kr
  unsigned short* ctx  = (unsigned short*)alloc((size_t)4096 * 768 * 2);

  CvtArgs ca;
  const float* srcs[8] = {x, Wq, Wk, Wv, Wpq, Wpk, Wo, rel};
  unsigned short* dsts[8] = {xb, Wqb, Wkb, Wvb, Wpqb, Wpkb, Wob, relb};
  const int nch[8] = {786432, 147456, 147456, 147456, 147456, 147456, 147456, 196800};
  int total = 0;
  for (int i = 0; i < 8; ++i) { ca.src[i] = srcs[i]; ca.dst[i] = dsts[i]; ca.nchunks[i] = nch[i]; total += nch[i]; }
  cvt_kernel<<<dim3(2048), dim3(256), 0, stream>>>(ca, total);

  dim3 blk(256);
  // merged QKV + REL projections (1356 blocks, one launch)
  gemm_qkvrel<<<dim3(1356), blk, 0, stream>>>(xb, Wqb, relb, Wpqb, Qb, qkx,
                                              bq, bk, bv, bpq, bpk);
  // fused scores(cc+cp+pc) + softmax + PV  (768 blocks, XCD-swizzled, 3/CU)
  flash_kernel<<<dim3(768), blk, 0, stream>>>(Qb, Kb, qkx + 787200, qkx, Vt, ctx);
  // output projection: [4096,768] x [768,768]^T -> fp32 d_out
  gemm_out<<<dim3(6, 64), blk, 0, stream>>>(ctx, Wob, (float*)d_out, bo);

  (void)in_sizes; (void)n_in; (void)out_size; (void)ws_size;
}

// Round 16
// 186.454 us; speedup vs baseline: 1.1967x; 1.0307x over previous
//
#include <hip/hip_runtime.h>
#include <stdint.h>

typedef __attribute__((ext_vector_type(8))) short bf8_t;   // 8 x bf16 (raw bits)
typedef __attribute__((ext_vector_type(4))) float f4_t;

#define DEV __device__ __forceinline__

constexpr int S_ = 1024;
constexpr float SCALE2_ = 0.104117584f;   // 1/sqrt(192) * log2(e)

DEV float bf2f(unsigned short u) { union { unsigned int i; float f; } v; v.i = ((unsigned int)u) << 16; return v.f; }
DEV unsigned short f2bf(float f) {
  union { float fv; unsigned int i; } v; v.fv = f;
  unsigned int r = v.i + 0x7FFFu + ((v.i >> 16) & 1u);
  return (unsigned short)(r >> 16);
}

DEV void gll16(const unsigned short* g, unsigned short* l) {
  __builtin_amdgcn_global_load_lds(
      (const __attribute__((address_space(1))) unsigned int*)g,
      (__attribute__((address_space(3))) unsigned int*)l, 16, 0, 0);
}

// 128B-row LDS tile, chunk-XOR swizzled
DEV const bf8_t* chunk128(const unsigned short* base, int row, int ck) {
  return (const bf8_t*)((const char*)base + row * 128 + (((ck ^ row) & 7) << 4));
}

// ---------------- fp32 -> bf16 bulk conversion (8 tensors, one launch) ----
struct CvtArgs { const float* src[8]; unsigned short* dst[8]; int nchunks[8]; };

__global__ __launch_bounds__(256) void cvt_kernel(CvtArgs a, int total) {
  int idx = blockIdx.x * 256 + threadIdx.x;
  int step = gridDim.x * 256;
  for (; idx < total; idx += step) {
    int c = idx, s = 0;
    while (c >= a.nchunks[s]) { c -= a.nchunks[s]; ++s; }
    float4 v = ((const float4*)a.src[s])[c];
    ushort4 o;
    o.x = f2bf(v.x); o.y = f2bf(v.y); o.z = f2bf(v.z); o.w = f2bf(v.w);
    ((ushort4*)a.dst[s])[c] = o;
  }
}

// ---- merged QKV + REL projections: one launch, 1356 blocks ---------------
__global__ __launch_bounds__(256) void gemm_qkvrel(
    const unsigned short* __restrict__ xb, const unsigned short* __restrict__ Wqkv,
    const unsigned short* __restrict__ relb, const unsigned short* __restrict__ Wrel,
    unsigned short* __restrict__ Cqkv, unsigned short* __restrict__ Crel,
    const float* __restrict__ bq, const float* __restrict__ bk, const float* __restrict__ bv,
    const float* __restrict__ bpq, const float* __restrict__ bpk)
{
  __shared__ unsigned short At[64 * 64];
  __shared__ unsigned short Bt[128 * 64];
  const int tid = threadIdx.x, lane = tid & 63, w = tid >> 6;
  const int li = lane & 15, g = lane >> 4;
  const int wr = w >> 1, wc = w & 1;

  const int bid = blockIdx.x;
  const bool qkv = bid < 1152;
  const unsigned short *A, *B;
  int m0, n0, M, N;
  if (qkv) { m0 = (bid / 18) * 64; n0 = (bid % 18) * 128; A = xb;   B = Wqkv; M = 4096; N = 2304; }
  else     { int t = bid - 1152;
             m0 = (t / 12) * 64;  n0 = (t % 12) * 128;  A = relb; B = Wrel; M = 1025; N = 1536; }

  const int srow = tid >> 3;
  const int sl = (tid & 7) ^ (srow & 7);
  const long aoff0 = (long)min(m0 + srow,      M - 1) * 768 + sl * 8;
  const long aoff1 = (long)min(m0 + srow + 32, M - 1) * 768 + sl * 8;
  const long boff0 = (long)min(n0 + srow,      N - 1) * 768 + sl * 8;
  const long boff1 = (long)min(n0 + srow + 32, N - 1) * 768 + sl * 8;
  const long boff2 = (long)min(n0 + srow + 64, N - 1) * 768 + sl * 8;
  const long boff3 = (long)min(n0 + srow + 96, N - 1) * 768 + sl * 8;

  f4_t acc[2][4];
#pragma unroll
  for (int i = 0; i < 2; ++i)
#pragma unroll
    for (int j = 0; j < 4; ++j) acc[i][j] = f4_t{0.f, 0.f, 0.f, 0.f};

  for (int k0 = 0; k0 < 768; k0 += 64) {
    gll16(A + aoff0 + k0, At + tid * 8);
    gll16(A + aoff1 + k0, At + tid * 8 + 2048);
    gll16(B + boff0 + k0, Bt + tid * 8);
    gll16(B + boff1 + k0, Bt + tid * 8 + 2048);
    gll16(B + boff2 + k0, Bt + tid * 8 + 4096);
    gll16(B + boff3 + k0, Bt + tid * 8 + 6144);
    asm volatile("s_waitcnt vmcnt(0)" ::: "memory");
    __syncthreads();
#pragma unroll
    for (int ks = 0; ks < 2; ++ks) {
      bf8_t a[2], b[4];
#pragma unroll
      for (int fm = 0; fm < 2; ++fm)
        a[fm] = *chunk128(At, wr * 32 + fm * 16 + li, ks * 4 + g);
#pragma unroll
      for (int fn = 0; fn < 4; ++fn)
        b[fn] = *chunk128(Bt, wc * 64 + fn * 16 + li, ks * 4 + g);
#pragma unroll
      for (int fm = 0; fm < 2; ++fm)
#pragma unroll
        for (int fn = 0; fn < 4; ++fn)
          acc[fm][fn] = __builtin_amdgcn_mfma_f32_16x16x32_bf16(a[fm], b[fn], acc[fm][fn], 0, 0, 0);
    }
    __syncthreads();
  }

#pragma unroll
  for (int fm = 0; fm < 2; ++fm)
#pragma unroll
    for (int fn = 0; fn < 4; ++fn)
#pragma unroll
      for (int r = 0; r < 4; ++r) {
        int m = m0 + wr * 32 + fm * 16 + g * 4 + r;
        int n = n0 + wc * 64 + fn * 16 + li;
        if (m >= M || n >= N) continue;
        float v = acc[fm][fn][r];
        if (qkv) {
          int sel = (n >= 1536) ? 2 : (n >= 768 ? 1 : 0);
          int nn = n - sel * 768;
          v += (sel == 0 ? bq : sel == 1 ? bk : bv)[nn];
          long off = (long)sel * 3145728 + (long)((m >> 10) * 12 + (nn >> 6)) * 65536;
          if (sel == 2) off += (nn & 63) * 1024 + (m & 1023);   // V transposed
          else          off += (m & 1023) * 64 + (nn & 63);
          Cqkv[off] = f2bf(v);
        } else {
          // compact tables: [2 tbl][12 h][1025 t][64 d]
          int sel = n >= 768 ? 1 : 0;
          int nn = n - sel * 768;
          v += (sel ? bpk : bpq)[nn];
          long off = (long)sel * 787200 + (long)(nn >> 6) * 65600 + (long)m * 64 + (nn & 63);
          Crel[off] = f2bf(v);
        }
      }
}

// ---- output projection GEMM: C(fp32) = A * B^T + bias --------------------
__global__ __launch_bounds__(256) void gemm_out(
    const unsigned short* __restrict__ A,
    const unsigned short* __restrict__ B,
    float* __restrict__ C, const float* __restrict__ b0)
{
  __shared__ unsigned short At[64 * 64];
  __shared__ unsigned short Bt[128 * 64];
  const int tid = threadIdx.x, lane = tid & 63, w = tid >> 6;
  const int li = lane & 15, g = lane >> 4;
  const int wr = w >> 1, wc = w & 1;
  const int m0 = blockIdx.y * 64, n0 = blockIdx.x * 128;

  const int srow = tid >> 3;
  const int sl = (tid & 7) ^ (srow & 7);
  const long aoff0 = (long)(m0 + srow) * 768 + sl * 8;
  const long aoff1 = (long)(m0 + srow + 32) * 768 + sl * 8;
  const long boff0 = (long)(n0 + srow) * 768 + sl * 8;
  const long boff1 = (long)(n0 + srow + 32) * 768 + sl * 8;
  const long boff2 = (long)(n0 + srow + 64) * 768 + sl * 8;
  const long boff3 = (long)(n0 + srow + 96) * 768 + sl * 8;

  f4_t acc[2][4];
#pragma unroll
  for (int i = 0; i < 2; ++i)
#pragma unroll
    for (int j = 0; j < 4; ++j) acc[i][j] = f4_t{0.f, 0.f, 0.f, 0.f};

  for (int k0 = 0; k0 < 768; k0 += 64) {
    gll16(A + aoff0 + k0, At + tid * 8);
    gll16(A + aoff1 + k0, At + tid * 8 + 2048);
    gll16(B + boff0 + k0, Bt + tid * 8);
    gll16(B + boff1 + k0, Bt + tid * 8 + 2048);
    gll16(B + boff2 + k0, Bt + tid * 8 + 4096);
    gll16(B + boff3 + k0, Bt + tid * 8 + 6144);
    asm volatile("s_waitcnt vmcnt(0)" ::: "memory");
    __syncthreads();
#pragma unroll
    for (int ks = 0; ks < 2; ++ks) {
      bf8_t a[2], b[4];
#pragma unroll
      for (int fm = 0; fm < 2; ++fm)
        a[fm] = *chunk128(At, wr * 32 + fm * 16 + li, ks * 4 + g);
#pragma unroll
      for (int fn = 0; fn < 4; ++fn)
        b[fn] = *chunk128(Bt, wc * 64 + fn * 16 + li, ks * 4 + g);
#pragma unroll
      for (int fm = 0; fm < 2; ++fm)
#pragma unroll
        for (int fn = 0; fn < 4; ++fn)
          acc[fm][fn] = __builtin_amdgcn_mfma_f32_16x16x32_bf16(a[fm], b[fn], acc[fm][fn], 0, 0, 0);
    }
    __syncthreads();
  }

#pragma unroll
  for (int fm = 0; fm < 2; ++fm)
#pragma unroll
    for (int fn = 0; fn < 4; ++fn)
#pragma unroll
      for (int r = 0; r < 4; ++r) {
        int m = m0 + wr * 32 + fm * 16 + g * 4 + r;
        int n = n0 + wc * 64 + fn * 16 + li;
        C[(long)m * 768 + n] = acc[fm][fn][r] + b0[n];
      }
}

// ------- fused flash (r13 body + T5 setprio around MFMA clusters) ---------
__global__ __launch_bounds__(256) void flash_kernel(
    const unsigned short* __restrict__ Q, const unsigned short* __restrict__ Kc,
    const unsigned short* __restrict__ kr, const unsigned short* __restrict__ qr,
    const unsigned short* __restrict__ Vt, unsigned short* __restrict__ ctx)
{
  // bijective XCD swizzle: each XCD owns 6 whole bh (all 16 i-tiles together)
  const int flat = blockIdx.x;
  const int logical = (flat & 7) * 96 + (flat >> 3);
  const int bh = logical >> 4, h = bh % 12, bb = bh / 12;
  const int i0 = (logical & 15) * 64;
  const int tid = threadIdx.x, lane = tid & 63, w = tid >> 6;
  const int g = lane >> 4, li = lane & 15;
  const unsigned short* Qb  = Q  + (long)bh * (S_ * 64);
  const unsigned short* Kb  = Kc + (long)bh * (S_ * 64);
  const unsigned short* Vb  = Vt + (long)bh * (S_ * 64);   // [64 d][1024 s]
  const unsigned short* krh = kr + (long)h * 65600;        // compact [1025][64]
  const unsigned short* qrh = qr + (long)h * 65600;

  __shared__ unsigned short Kt[4096];        // single buf, 64x64, XOR-swizzled chunks
  __shared__ unsigned short Vl[4096];        // single buf
  __shared__ unsigned short Tpc[64][132];
  __shared__ unsigned short TcpW[4][16][84]; // per-wave cp strips (42 dw/row)
  __shared__ unsigned short Pl[4096];        // per-wave P rows, XOR-swizzled

  const int mh = w & 1, nq = w >> 1;

  // stage K-tile + V-tile for tile jt (source-preswizzled, linear LDS dest)
  const int sr0 = w * 8 + (lane >> 3);
  const int scc = (lane & 7) ^ (sr0 & 7);
  auto stage = [&](int jt) {
    const int j0n = jt * 64;
    gll16(Kb + (long)(j0n + sr0) * 64 + scc * 8,        &Kt[w * 512 + lane * 8]);
    gll16(Kb + (long)(j0n + sr0 + 32) * 64 + scc * 8,   &Kt[w * 512 + 2048 + lane * 8]);
    gll16(Vb + (long)sr0 * 1024 + j0n + scc * 8,        &Vl[w * 512 + lane * 8]);
    gll16(Vb + (long)(sr0 + 32) * 1024 + j0n + scc * 8, &Vl[w * 512 + 2048 + lane * 8]);
  };

  // hoisted Q fragments: wave w owns rows i0 + w*16 .. +16
  bf8_t q3[2];
#pragma unroll
  for (int ks = 0; ks < 2; ++ks)
    q3[ks] = *(const bf8_t*)(Qb + (long)(i0 + w * 16 + li) * 64 + ks * 32 + g * 8);

  // no-max softmax: per-lane partial denominators, reduced once at epilogue
  float l_p[4] = {0.f, 0.f, 0.f, 0.f};
  f4_t acc_o[4];
#pragma unroll
  for (int fn = 0; fn < 4; ++fn) acc_o[fn] = f4_t{0.f, 0.f, 0.f, 0.f};

  const int base_cp = li + 15 - g * 4;          // + fn*16 - r  -> [0,78]
  const int base_pc = 63 + w * 16 + g * 4 - li; // + r - fn*16  -> [0,126]

  stage(0);

  for (int jt = 0; jt < 16; ++jt) {
    const int j0 = jt * 64;
    const int Dl = j0 - i0;
    const int wbU = Dl - w * 16 - 15 + 512;     // unclamped strip base
    const int rbU = 449 - Dl;                   // unclamped Tpc window base

    { // Tcp phase (regs + own strip; no K/V dep — covers stage latency)
      f4_t at[5];
#pragma unroll
      for (int f5 = 0; f5 < 5; ++f5) at[f5] = f4_t{0.f, 0.f, 0.f, 0.f};
#pragma unroll
      for (int ks = 0; ks < 2; ++ks) {
        bf8_t b[5];
#pragma unroll
        for (int f5 = 0; f5 < 5; ++f5) {
          int krow = min(max(wbU + f5 * 16 + li, 0), 1024);   // per-row clamp
          b[f5] = *(const bf8_t*)(krh + (long)krow * 64 + ks * 32 + g * 8);
        }
        __builtin_amdgcn_s_setprio(1);
#pragma unroll
        for (int f5 = 0; f5 < 5; ++f5)
          at[f5] = __builtin_amdgcn_mfma_f32_16x16x32_bf16(q3[ks], b[f5], at[f5], 0, 0, 0);
        __builtin_amdgcn_s_setprio(0);
      }
#pragma unroll
      for (int f5 = 0; f5 < 5; ++f5)
#pragma unroll
        for (int r = 0; r < 4; ++r)
          TcpW[w][g * 4 + r][f5 * 16 + li] = f2bf(at[f5][r]);
    }

    asm volatile("s_waitcnt vmcnt(0)" ::: "memory");
    __builtin_amdgcn_s_barrier();              // A: K,V staged & visible

    { // Tpc = Ktile(64x64) @ qrWin(128x64)^T  (A from swizzled LDS)
      f4_t acc[2][4];
#pragma unroll
      for (int i = 0; i < 2; ++i)
#pragma unroll
        for (int j = 0; j < 4; ++j) acc[i][j] = f4_t{0.f, 0.f, 0.f, 0.f};
#pragma unroll
      for (int ks = 0; ks < 2; ++ks) {
        bf8_t a[2], b[4];
#pragma unroll
        for (int fm = 0; fm < 2; ++fm)
          a[fm] = *chunk128(Kt, mh * 32 + fm * 16 + li, ks * 4 + g);
#pragma unroll
        for (int fn = 0; fn < 4; ++fn) {
          int qrow = min(max(rbU + nq * 64 + fn * 16 + li, 0), 1024);  // per-row clamp
          b[fn] = *(const bf8_t*)(qrh + (long)qrow * 64 + ks * 32 + g * 8);
        }
        __builtin_amdgcn_s_setprio(1);
#pragma unroll
        for (int fm = 0; fm < 2; ++fm)
#pragma unroll
          for (int fn = 0; fn < 4; ++fn)
            acc[fm][fn] = __builtin_amdgcn_mfma_f32_16x16x32_bf16(a[fm], b[fn], acc[fm][fn], 0, 0, 0);
        __builtin_amdgcn_s_setprio(0);
      }
#pragma unroll
      for (int fm = 0; fm < 2; ++fm)
#pragma unroll
        for (int fn = 0; fn < 4; ++fn)
#pragma unroll
          for (int r = 0; r < 4; ++r)
            Tpc[mh * 32 + fm * 16 + g * 4 + r][nq * 64 + fn * 16 + li] = f2bf(acc[fm][fn][r]);
    }

    asm volatile("s_waitcnt lgkmcnt(0)" ::: "memory");
    __builtin_amdgcn_s_barrier();              // B: Tpc visible

    // cc MFMA — wave w: rows [w*16, w*16+16), all 64 cols
    f4_t s4[4];
#pragma unroll
    for (int fn = 0; fn < 4; ++fn) s4[fn] = f4_t{0.f, 0.f, 0.f, 0.f};
#pragma unroll
    for (int ks = 0; ks < 2; ++ks) {
      bf8_t b[4];
#pragma unroll
      for (int fn = 0; fn < 4; ++fn)
        b[fn] = *chunk128(Kt, fn * 16 + li, ks * 4 + g);
      __builtin_amdgcn_s_setprio(1);
#pragma unroll
      for (int fn = 0; fn < 4; ++fn)
        s4[fn] = __builtin_amdgcn_mfma_f32_16x16x32_bf16(q3[ks], b[fn], s4[fn], 0, 0, 0);
      __builtin_amdgcn_s_setprio(0);
    }

    // gather cp + pc; exp2 (no max subtraction); partial denom; P to LDS
#pragma unroll
    for (int fn = 0; fn < 4; ++fn)
#pragma unroll
      for (int r = 0; r < 4; ++r) {
        float v = s4[fn][r] + bf2f(TcpW[w][g * 4 + r][base_cp + fn * 16 - r])
                            + bf2f(Tpc[fn * 16 + li][base_pc + r - fn * 16]);
        float p = exp2f(v * SCALE2_);
        l_p[r] += p;
        const int row = w * 16 + g * 4 + r;
        int byte = row * 128 + (fn * 16 + li) * 2;
        byte ^= (row & 7) << 4;
        *(unsigned short*)((char*)Pl + byte) = f2bf(p);
      }

    // PV: acc_o += P(16x64) @ V^T
#pragma unroll
    for (int ks = 0; ks < 2; ++ks) {
      const int arow = w * 16 + li;
      int abyte = arow * 128 + ks * 64 + g * 16;
      abyte ^= (arow & 7) << 4;
      bf8_t a = *(const bf8_t*)((const char*)Pl + abyte);
      bf8_t b[4];
#pragma unroll
      for (int fn2 = 0; fn2 < 4; ++fn2)
        b[fn2] = *chunk128(Vl, fn2 * 16 + li, ks * 4 + g);
      __builtin_amdgcn_s_setprio(1);
#pragma unroll
      for (int fn2 = 0; fn2 < 4; ++fn2)
        acc_o[fn2] = __builtin_amdgcn_mfma_f32_16x16x32_bf16(a, b[fn2], acc_o[fn2], 0, 0, 0);
      __builtin_amdgcn_s_setprio(0);
    }

    if (jt + 1 < 16) {
      __builtin_amdgcn_s_barrier();            // C: all waves done reading Kt/Vl
      stage(jt + 1);                            // latency covered by next Tcp phase
    }
  }

  // epilogue: one 16-lane reduction of the deferred denominators, then write
#pragma unroll
  for (int r = 0; r < 4; ++r)
#pragma unroll
    for (int off = 1; off < 16; off <<= 1) l_p[r] += __shfl_xor(l_p[r], off);
  float inv[4];
#pragma unroll
  for (int r = 0; r < 4; ++r) inv[r] = 1.0f / l_p[r];
#pragma unroll
  for (int fn2 = 0; fn2 < 4; ++fn2)
#pragma unroll
    for (int r = 0; r < 4; ++r) {
      const int row = i0 + w * 16 + g * 4 + r;
      const int d = fn2 * 16 + li;
      float v = acc_o[fn2][r] * inv[r];
      ctx[((long)bb * 1024 + row) * 768 + h * 64 + d] = f2bf(v);
    }
}

// ---------------- host launch ---------------------------------------------
extern "C" void kernel_launch(void* const* d_in, const int* in_sizes, int n_in,
                              void* d_out, int out_size, void* d_ws, size_t ws_size,
                              hipStream_t stream)
{
  const float* x   = (const float*)d_in[0];
  const float* Wq  = (const float*)d_in[1];
  const float* bq  = (const float*)d_in[2];
  const float* Wk  = (const float*)d_in[3];
  const float* bk  = (const float*)d_in[4];
  const float* Wv  = (const float*)d_in[5];
  const float* bv  = (const float*)d_in[6];
  const float* Wpq = (const float*)d_in[7];
  const float* bpq = (const float*)d_in[8];
  const float* Wpk = (const float*)d_in[9];
  const float* bpk = (const float*)d_in[10];
  const float* rel = (const float*)d_in[11];
  const float* Wo  = (const float*)d_in[12];
  const float* bo  = (const float*)d_in[13];

  char* ws = (char*)d_ws;
  auto alloc = [&](size_t bytes) { char* p = ws; ws += (bytes + 255) & ~(size_t)255; return p; };
  unsigned short* xb   = (unsigned short*)alloc((size_t)4096 * 768 * 2);
  unsigned short* Wqb  = (unsigned short*)alloc((size_t)768 * 768 * 2);   // contiguous Wq|Wk|Wv
  unsigned short* Wkb  = (unsigned short*)alloc((size_t)768 * 768 * 2);
  unsigned short* Wvb  = (unsigned short*)alloc((size_t)768 * 768 * 2);
  unsigned short* Wpqb = (unsigned short*)alloc((size_t)768 * 768 * 2);   // contiguous Wpq|Wpk
  unsigned short* Wpkb = (unsigned short*)alloc((size_t)768 * 768 * 2);
  unsigned short* Wob  = (unsigned short*)alloc((size_t)768 * 768 * 2);
  unsigned short* relb = (unsigned short*)alloc((size_t)1025 * 768 * 2);
  unsigned short* Qb   = (unsigned short*)alloc((size_t)48 * 1024 * 64 * 2);  // contiguous Q|K|Vt
  unsigned short* Kb   = (unsigned short*)alloc((size_t)48 * 1024 * 64 * 2);
  unsigned short* Vt   = (unsigned short*)alloc((size_t)48 * 64 * 1024 * 2);
  unsigned short* qkx  = (unsigned short*)alloc((size_t)2 * 12 * 1025 * 64 * 2); // compact qr|kr
  unsigned short* ctx  = (unsigned short*)alloc((size_t)4096 * 768 * 2);

  CvtArgs ca;
  const float* srcs[8] = {x, Wq, Wk, Wv, Wpq, Wpk, Wo, rel};
  unsigned short* dsts[8] = {xb, Wqb, Wkb, Wvb, Wpqb, Wpkb, Wob, relb};
  const int nch[8] = {786432, 147456, 147456, 147456, 147456, 147456, 147456, 196800};
  int total = 0;
  for (int i = 0; i < 8; ++i) { ca.src[i] = srcs[i]; ca.dst[i] = dsts[i]; ca.nchunks[i] = nch[i]; total += nch[i]; }
  cvt_kernel<<<dim3(2048), dim3(256), 0, stream>>>(ca, total);

  dim3 blk(256);
  // merged QKV + REL projections (1356 blocks, one launch)
  gemm_qkvrel<<<dim3(1356), blk, 0, stream>>>(xb, Wqb, relb, Wpqb, Qb, qkx,
                                              bq, bk, bv, bpq, bpk);
  // fused scores(cc+cp+pc) + softmax + PV  (768 blocks, XCD-swizzled, 3/CU)
  flash_kernel<<<dim3(768), blk, 0, stream>>>(Qb, Kb, qkx + 787200, qkx, Vt, ctx);
  // output projection: [4096,768] x [768,768]^T -> fp32 d_out
  gemm_out<<<dim3(6, 64), blk, 0, stream>>>(ctx, Wob, (float*)d_out, bo);

  (void)in_sizes; (void)n_in; (void)out_size; (void)ws_size;
}